// Round 1
// baseline (1062.881 us; speedup 1.0000x reference)
//
#include <hip/hip_runtime.h>
#include <cstdint>
#include <cstddef>

// GRU cell fused as two f16-MFMA GEMMs.
// M = BATCH*NUM_CITIES = 131072 rows, A=128 attrs, H=512 hiddens, K = A+H = 640.
// K1: [x|h] @ [[wz,wr],[uz,ur]]  -> z (fp32, staged in d_out), rh = sigmoid(ar)*h (f16, ws)
// K2: [x|rh] @ [[wh],[uh]]       -> h_new = (1-z)*h + z*tanh(ah)  (overwrites d_out)

#define M_ROWS 131072
#define A_DIM 128
#define H_DIM 512
#define K_TOT 640
#define BM 128
#define BN 128
#define BK 32
#define NSTEPS 20  // K_TOT / BK
#define XSTEPS 4   // A_DIM / BK

typedef _Float16 f16;
typedef _Float16 f16x8 __attribute__((ext_vector_type(8)));
typedef float f32x4 __attribute__((ext_vector_type(4)));

// LDS tile layout: [128 rows][32 k] f16 = 64 B/row, 4x 16B slots per row.
// XOR swizzle slot^(row&3) spreads the stride-64B fragment reads across bank groups.
__device__ __forceinline__ uint32_t swz(int row, int slot) {
  return (uint32_t)((row << 6) + (((slot) ^ (row & 3)) << 4));
}

__device__ __forceinline__ float sigmoid_f(float v) { return 1.0f / (1.0f + __expf(-v)); }
__device__ __forceinline__ float tanh_f(float v) {
  float c = fminf(fmaxf(v, -15.0f), 15.0f);
  float e = __expf(2.0f * c);
  return (e - 1.0f) / (e + 1.0f);
}

__device__ __forceinline__ void cvt_store(void* dst, float4 a, float4 b) {
  f16x8 v;
  v[0] = (_Float16)a.x; v[1] = (_Float16)a.y; v[2] = (_Float16)a.z; v[3] = (_Float16)a.w;
  v[4] = (_Float16)b.x; v[5] = (_Float16)b.y; v[6] = (_Float16)b.z; v[7] = (_Float16)b.w;
  *(f16x8*)dst = v;
}

// Build transposed, f16 weight panels in ws:
//  B1t [1024][640]: n<512 -> (wz|uz) column n ; n>=512 -> (wr|ur) column n-512
//  B2t [ 512][640]: (wh|uh) column n
__global__ void build_wcat(const float* __restrict__ wz, const float* __restrict__ uz,
                           const float* __restrict__ wr, const float* __restrict__ ur,
                           const float* __restrict__ wh, const float* __restrict__ uh,
                           f16* __restrict__ B1, f16* __restrict__ B2) {
  int idx = blockIdx.x * blockDim.x + threadIdx.x;
  const int n1 = 1024 * K_TOT;
  if (idx < n1) {
    int n = idx / K_TOT, k = idx % K_TOT;
    float v;
    if (k < A_DIM) v = (n < H_DIM) ? wz[k * H_DIM + n] : wr[k * H_DIM + (n - H_DIM)];
    else           v = (n < H_DIM) ? uz[(k - A_DIM) * H_DIM + n] : ur[(k - A_DIM) * H_DIM + (n - H_DIM)];
    B1[idx] = (f16)v;
  } else {
    int idx2 = idx - n1;
    if (idx2 < H_DIM * K_TOT) {
      int n = idx2 / K_TOT, k = idx2 % K_TOT;
      float v = (k < A_DIM) ? wh[k * H_DIM + n] : uh[(k - A_DIM) * H_DIM + n];
      B2[idx2] = (f16)v;
    }
  }
}

// MODE 1: N_TOT=1024 (z | r).  MODE 2: N_TOT=512 (h_tilde pre-act).
template <int MODE>
__global__ __launch_bounds__(256, 2)
void gru_gemm(const float* __restrict__ x, const float* __restrict__ h,
              const f16* __restrict__ Bt, const f16* __restrict__ rh_in,
              const float* __restrict__ bias0, const float* __restrict__ bias1,
              float* __restrict__ out, f16* __restrict__ rh_out) {
  constexpr int NBLK = (MODE == 1) ? 8 : 4;
  __shared__ __align__(16) char smem[2 * 16384];  // 2 bufs x (A 8KB + B 8KB)

  const int bid = blockIdx.x;
  const int nb = bid & (NBLK - 1);   // n fastest: consecutive blocks share the A panel (L2 reuse)
  const int mb = bid / NBLK;
  const int m0 = mb * BM;
  const int n0 = nb * BN;

  const int tid = threadIdx.x;
  const int lane = tid & 63;
  const int wid = tid >> 6;
  const int wm = wid >> 1;
  const int wn = wid & 1;
  const int r16 = lane & 15;
  const int kh = lane >> 4;

  // staging map: 2 threads per row, each covers 16 k (2 x 16B slots)
  const int row = tid >> 1;
  const int sbase = (tid & 1) * 2;

  f32x4 acc[4][4];
#pragma unroll
  for (int i = 0; i < 4; ++i)
#pragma unroll
    for (int j = 0; j < 4; ++j) acc[i][j] = (f32x4){0.f, 0.f, 0.f, 0.f};

  float4 fa0, fa1, fa2, fa3;
  int4 ia0, ia1, ib0, ib1;

  auto load_t = [&](int t) {
    const f16* gB = Bt + (size_t)(n0 + row) * K_TOT + t * BK + sbase * 8;
    ib0 = *(const int4*)gB;
    ib1 = *(const int4*)(gB + 8);
    if (MODE == 2 && t >= XSTEPS) {
      const f16* gA = rh_in + (size_t)(m0 + row) * H_DIM + (t * BK - A_DIM) + sbase * 8;
      ia0 = *(const int4*)gA;
      ia1 = *(const int4*)(gA + 8);
    } else {
      const float* src = (t < XSTEPS) ? x : h;
      const int ldg = (t < XSTEPS) ? A_DIM : H_DIM;
      const int col = (t < XSTEPS) ? t * BK : t * BK - A_DIM;
      const float* gA = src + (size_t)(m0 + row) * ldg + col + sbase * 8;
      fa0 = *(const float4*)gA;
      fa1 = *(const float4*)(gA + 4);
      fa2 = *(const float4*)(gA + 8);
      fa3 = *(const float4*)(gA + 12);
    }
  };
  auto write_t = [&](int t, int buf) {
    char* Aw = smem + buf * 16384;
    char* Bw = Aw + 8192;
    *(int4*)(Bw + swz(row, sbase)) = ib0;
    *(int4*)(Bw + swz(row, sbase + 1)) = ib1;
    if (MODE == 2 && t >= XSTEPS) {
      *(int4*)(Aw + swz(row, sbase)) = ia0;
      *(int4*)(Aw + swz(row, sbase + 1)) = ia1;
    } else {
      cvt_store(Aw + swz(row, sbase), fa0, fa1);
      cvt_store(Aw + swz(row, sbase + 1), fa2, fa3);
    }
  };

  load_t(0);
  write_t(0, 0);
  __syncthreads();

  int cur = 0;
  for (int t = 0; t < NSTEPS; ++t) {
    if (t + 1 < NSTEPS) load_t(t + 1);  // issue next-tile global loads early
    const char* Al = smem + cur * 16384;
    const char* Bl = Al + 8192;
    f16x8 aF[4], bF[4];
#pragma unroll
    for (int mi = 0; mi < 4; ++mi)
      aF[mi] = *(const f16x8*)(Al + swz(wm * 64 + mi * 16 + r16, kh));
#pragma unroll
    for (int ni = 0; ni < 4; ++ni)
      bF[ni] = *(const f16x8*)(Bl + swz(wn * 64 + ni * 16 + r16, kh));
#pragma unroll
    for (int mi = 0; mi < 4; ++mi)
#pragma unroll
      for (int ni = 0; ni < 4; ++ni)
        acc[mi][ni] = __builtin_amdgcn_mfma_f32_16x16x32_f16(aF[mi], bF[ni], acc[mi][ni], 0, 0, 0);
    if (t + 1 < NSTEPS) write_t(t + 1, cur ^ 1);
    __syncthreads();
    cur ^= 1;
  }

  // epilogue: C/D layout col=lane&15, row=(lane>>4)*4+reg (m89/m91-verified)
#pragma unroll
  for (int mi = 0; mi < 4; ++mi) {
#pragma unroll
    for (int ni = 0; ni < 4; ++ni) {
      const int n_g = n0 + wn * 64 + ni * 16 + r16;
#pragma unroll
      for (int r = 0; r < 4; ++r) {
        const int m_g = m0 + wm * 64 + mi * 16 + kh * 4 + r;
        float v = acc[mi][ni][r];
        if (MODE == 1) {
          if (n_g < H_DIM) {
            out[(size_t)m_g * H_DIM + n_g] = sigmoid_f(v + bias0[n_g]);
          } else {
            const int j = n_g - H_DIM;
            float rv = sigmoid_f(v + bias1[j]);
            float rhv = rv * h[(size_t)m_g * H_DIM + j];
            rh_out[(size_t)m_g * H_DIM + j] = (f16)rhv;
          }
        } else {
          float th = tanh_f(v + bias0[n_g]);
          const size_t off = (size_t)m_g * H_DIM + n_g;
          float zv = out[off];     // z written by kernel 1
          float hv = h[off];
          out[off] = (1.0f - zv) * hv + zv * th;
        }
      }
    }
  }
}

extern "C" void kernel_launch(void* const* d_in, const int* in_sizes, int n_in,
                              void* d_out, int out_size, void* d_ws, size_t ws_size,
                              hipStream_t stream) {
  const float* x  = (const float*)d_in[0];
  const float* h  = (const float*)d_in[1];
  const float* wz = (const float*)d_in[2];
  const float* uz = (const float*)d_in[3];
  const float* bz = (const float*)d_in[4];
  const float* wr = (const float*)d_in[5];
  const float* ur = (const float*)d_in[6];
  const float* br = (const float*)d_in[7];
  const float* wh = (const float*)d_in[8];
  const float* uh = (const float*)d_in[9];
  const float* bh = (const float*)d_in[10];
  float* out = (float*)d_out;

  char* ws = (char*)d_ws;
  f16* B1 = (f16*)ws;                                            // 1024*640*2 = 1,310,720 B
  f16* B2 = (f16*)(ws + (size_t)1024 * K_TOT * 2);               //  512*640*2 =   655,360 B
  f16* rh = (f16*)(ws + (size_t)1024 * K_TOT * 2
                      + (size_t)H_DIM * K_TOT * 2);              // M*512*2 = 134,217,728 B

  const int wtot = 1024 * K_TOT + H_DIM * K_TOT;  // 983040
  build_wcat<<<dim3((wtot + 255) / 256), dim3(256), 0, stream>>>(wz, uz, wr, ur, wh, uh, B1, B2);
  gru_gemm<1><<<dim3((M_ROWS / BM) * 8), dim3(256), 0, stream>>>(x, h, B1, nullptr, bz, br, out, rh);
  gru_gemm<2><<<dim3((M_ROWS / BM) * 4), dim3(256), 0, stream>>>(x, h, B2, rh, bh, nullptr, out, nullptr);
}

// Round 2
// 924.220 us; speedup vs baseline: 1.1500x; 1.1500x over previous
//
#include <hip/hip_runtime.h>
#include <cstdint>
#include <cstddef>

// GRU cell fused as two f16-MFMA GEMMs.
// M = 131072 rows, A=128, H=512, K = 640.
// K1: [x|h] @ [[wz,wr],[uz,ur]] -> z (f16 ws if room, else fp32 d_out), rh = sigmoid(ar)*h (f16 ws)
// K2: [x|rh] @ [[wh],[uh]]      -> h_new = h + z*(tanh(ah)-h)

#define M_ROWS 131072
#define A_DIM 128
#define H_DIM 512
#define K_TOT 640
#define BM 128
#define BN 128
#define BK 32
#define NSTEPS 20
#define XSTEPS 4

typedef _Float16 f16;
typedef _Float16 f16x8 __attribute__((ext_vector_type(8)));
typedef float f32x4 __attribute__((ext_vector_type(4)));

#define AS1 __attribute__((address_space(1)))
#define AS3 __attribute__((address_space(3)))

// async global->LDS, 16B per lane, LDS dest = wave-uniform base + lane*16 (linear)
__device__ __forceinline__ void gload_lds16(const void* g, void* l) {
  __builtin_amdgcn_global_load_lds((const AS1 unsigned int*)g,
                                   (AS3 unsigned int*)l, 16, 0, 0);
}

__device__ __forceinline__ float sigmoid_f(float v) { return 1.0f / (1.0f + __expf(-v)); }
__device__ __forceinline__ float tanh_f(float v) {
  float c = fminf(fmaxf(v, -15.0f), 15.0f);
  float e = __expf(2.0f * c);
  return (e - 1.0f) / (e + 1.0f);
}

__device__ __forceinline__ void cvt_store(void* dst, float4 a, float4 b) {
  f16x8 v;
  v[0] = (_Float16)a.x; v[1] = (_Float16)a.y; v[2] = (_Float16)a.z; v[3] = (_Float16)a.w;
  v[4] = (_Float16)b.x; v[5] = (_Float16)b.y; v[6] = (_Float16)b.z; v[7] = (_Float16)b.w;
  *(f16x8*)dst = v;
}

// Weight panels in ws (f16, transposed to [n][k]):
//  B1 [1024][640]: n<512 -> (wz|uz) col n ; n>=512 -> (wr|ur) col n-512
//  B2 [ 512][640]: (wh|uh) col n
__global__ void build_wcat(const float* __restrict__ wz, const float* __restrict__ uz,
                           const float* __restrict__ wr, const float* __restrict__ ur,
                           const float* __restrict__ wh, const float* __restrict__ uh,
                           f16* __restrict__ B1, f16* __restrict__ B2) {
  int idx = blockIdx.x * blockDim.x + threadIdx.x;
  const int n1 = 1024 * K_TOT;
  if (idx < n1) {
    int n = idx / K_TOT, k = idx % K_TOT;
    float v;
    if (k < A_DIM) v = (n < H_DIM) ? wz[k * H_DIM + n] : wr[k * H_DIM + (n - H_DIM)];
    else           v = (n < H_DIM) ? uz[(k - A_DIM) * H_DIM + n] : ur[(k - A_DIM) * H_DIM + (n - H_DIM)];
    B1[idx] = (f16)v;
  } else {
    int idx2 = idx - n1;
    if (idx2 < H_DIM * K_TOT) {
      int n = idx2 / K_TOT, k = idx2 % K_TOT;
      float v = (k < A_DIM) ? wh[k * H_DIM + n] : uh[(k - A_DIM) * H_DIM + n];
      B2[idx2] = (f16)v;
    }
  }
}

// MODE 1: N_TOT=1024 (z|r). MODE 2: N_TOT=512 (h_tilde pre-act).
// LDS tile: linear [128 rows][32 k] f16 (64 B/row). Fragment reads and staged
// writes are bank-balanced in this geometry (verified by bank math; no swizzle).
template <int MODE>
__global__ __launch_bounds__(256, 2)
void gru_gemm(const float* __restrict__ x, const float* __restrict__ h,
              const f16* __restrict__ Bt, const f16* __restrict__ rh_in,
              const float* __restrict__ bias0, const float* __restrict__ bias1,
              float* __restrict__ out, f16* __restrict__ rh_out,
              f16* __restrict__ zbuf) {
  constexpr int NBLK = (MODE == 1) ? 8 : 4;
  __shared__ __align__(16) char smem[2 * 16384];  // 2 bufs x (A 8KB + B 8KB)

  // XCD-bijective swizzle: grid is a multiple of 8; XCD x gets a contiguous
  // chunk of tiles, nb fastest within -> A panel + whole B panel are L2-local.
  const int per = gridDim.x >> 3;
  const int b = blockIdx.x;
  const int tile = (b & 7) * per + (b >> 3);
  const int nb = tile & (NBLK - 1);
  const int mb = tile / NBLK;
  const int m0 = mb * BM;
  const int n0 = nb * BN;

  const int tid = threadIdx.x;
  const int lane = tid & 63;
  const int wid = tid >> 6;
  const int wm = wid >> 1;
  const int wn = wid & 1;
  const int r16 = lane & 15;
  const int kh = lane >> 4;

  f32x4 acc[4][4];
#pragma unroll
  for (int i = 0; i < 4; ++i)
#pragma unroll
    for (int j = 0; j < 4; ++j) acc[i][j] = (f32x4){0.f, 0.f, 0.f, 0.f};

  float4 fa0, fa1, fa2, fa3;  // reg staging for fp32 A halves

  // ---- staging helpers ----
  auto dma_B = [&](int t, int buf) {
    char* Bw = smem + buf * 16384 + 8192;
#pragma unroll
    for (int i = 0; i < 2; ++i) {
      const int chunk = wid * 2 + i;
      const int s = chunk * 64 + lane;
      const int row = s >> 2, c = s & 3;
      const f16* g = Bt + (size_t)(n0 + row) * K_TOT + t * BK + c * 8;
      gload_lds16(g, Bw + chunk * 1024);
    }
  };
  auto dma_A_rh = [&](int t, int buf) {  // MODE 2, t>=XSTEPS: A half is f16 rh
    char* Aw = smem + buf * 16384;
    const int col = t * BK - A_DIM;
#pragma unroll
    for (int i = 0; i < 2; ++i) {
      const int chunk = wid * 2 + i;
      const int s = chunk * 64 + lane;
      const int row = s >> 2, c = s & 3;
      const f16* g = rh_in + (size_t)(m0 + row) * H_DIM + col + c * 8;
      gload_lds16(g, Aw + chunk * 1024);
    }
  };
  auto load_A_regs = [&](int t) {  // fp32 source (x or h)
    const float* src = (t < XSTEPS) ? x : h;
    const int ld = (t < XSTEPS) ? A_DIM : H_DIM;
    const int col = (t < XSTEPS) ? t * BK : t * BK - A_DIM;
    {
      const int s = tid, row = s >> 2, c = s & 3;
      const float* g = src + (size_t)(m0 + row) * ld + col + c * 8;
      fa0 = *(const float4*)g;
      fa1 = *(const float4*)(g + 4);
    }
    {
      const int s = tid + 256, row = s >> 2, c = s & 3;
      const float* g = src + (size_t)(m0 + row) * ld + col + c * 8;
      fa2 = *(const float4*)g;
      fa3 = *(const float4*)(g + 4);
    }
  };
  auto write_A = [&](int buf) {
    char* Aw = smem + buf * 16384;
    cvt_store(Aw + tid * 16, fa0, fa1);
    cvt_store(Aw + (tid + 256) * 16, fa2, fa3);
  };

  // ---- prologue (t=0; MODE2 t0 is the x half -> reg path) ----
  dma_B(0, 0);
  load_A_regs(0);
  write_A(0);
  __syncthreads();

  int cur = 0;
  for (int t = 0; t < NSTEPS; ++t) {
    const int nxt = t + 1;
    const bool have = nxt < NSTEPS;
    const bool nxt_dma_A = (MODE == 2) && (nxt >= XSTEPS);
    if (have) {
      dma_B(nxt, cur ^ 1);
      if (nxt_dma_A) dma_A_rh(nxt, cur ^ 1);
      else load_A_regs(nxt);
    }
    const char* Al = smem + cur * 16384;
    const char* Bl = Al + 8192;
    f16x8 aF[4], bF[4];
#pragma unroll
    for (int mi = 0; mi < 4; ++mi)
      aF[mi] = *(const f16x8*)(Al + (wm * 64 + mi * 16 + r16) * 64 + kh * 16);
#pragma unroll
    for (int ni = 0; ni < 4; ++ni)
      bF[ni] = *(const f16x8*)(Bl + (wn * 64 + ni * 16 + r16) * 64 + kh * 16);
#pragma unroll
    for (int mi = 0; mi < 4; ++mi)
#pragma unroll
      for (int ni = 0; ni < 4; ++ni)
        acc[mi][ni] = __builtin_amdgcn_mfma_f32_16x16x32_f16(aF[mi], bF[ni], acc[mi][ni], 0, 0, 0);
    if (have && !nxt_dma_A) write_A(cur ^ 1);
    __syncthreads();
    cur ^= 1;
  }

  // ---- epilogue: C/D layout col=lane&15, row=(lane>>4)*4+reg ----
#pragma unroll
  for (int mi = 0; mi < 4; ++mi) {
#pragma unroll
    for (int ni = 0; ni < 4; ++ni) {
      const int n_g = n0 + wn * 64 + ni * 16 + r16;
#pragma unroll
      for (int r = 0; r < 4; ++r) {
        const int m_g = m0 + wm * 64 + mi * 16 + kh * 4 + r;
        float v = acc[mi][ni][r];
        if (MODE == 1) {
          if (n_g < H_DIM) {
            float zv = sigmoid_f(v + bias0[n_g]);
            if (zbuf) zbuf[(size_t)m_g * H_DIM + n_g] = (f16)zv;
            else      out[(size_t)m_g * H_DIM + n_g] = zv;
          } else {
            const int j = n_g - H_DIM;
            const size_t off = (size_t)m_g * H_DIM + j;
            float rv = sigmoid_f(v + bias1[j]);
            rh_out[off] = (f16)(rv * h[off]);  // h row-panel is L2-warm (just streamed)
          }
        } else {
          const size_t off = (size_t)m_g * H_DIM + n_g;
          float th = tanh_f(v + bias0[n_g]);
          float zv = zbuf ? (float)zbuf[off] : out[off];
          float hv = h[off];
          out[off] = fmaf(zv, th - hv, hv);  // (1-z)h + z*th
        }
      }
    }
  }
}

extern "C" void kernel_launch(void* const* d_in, const int* in_sizes, int n_in,
                              void* d_out, int out_size, void* d_ws, size_t ws_size,
                              hipStream_t stream) {
  const float* x  = (const float*)d_in[0];
  const float* h  = (const float*)d_in[1];
  const float* wz = (const float*)d_in[2];
  const float* uz = (const float*)d_in[3];
  const float* bz = (const float*)d_in[4];
  const float* wr = (const float*)d_in[5];
  const float* ur = (const float*)d_in[6];
  const float* br = (const float*)d_in[7];
  const float* wh = (const float*)d_in[8];
  const float* uh = (const float*)d_in[9];
  const float* bh = (const float*)d_in[10];
  float* out = (float*)d_out;

  char* ws = (char*)d_ws;
  const size_t B1_B = (size_t)1024 * K_TOT * 2;   // 1,310,720
  const size_t B2_B = (size_t)H_DIM * K_TOT * 2;  //   655,360
  const size_t RH_B = (size_t)M_ROWS * H_DIM * 2; // 134,217,728
  f16* B1 = (f16*)ws;
  f16* B2 = (f16*)(ws + B1_B);
  f16* rh = (f16*)(ws + B1_B + B2_B);
  // z as f16 only if the workspace is big enough; else fall back to fp32 z in d_out.
  const bool use_z16 = ws_size >= (B1_B + B2_B + 2 * RH_B);
  f16* z16 = use_z16 ? (f16*)(ws + B1_B + B2_B + RH_B) : nullptr;

  const int wtot = 1024 * K_TOT + H_DIM * K_TOT;
  build_wcat<<<dim3((wtot + 255) / 256), dim3(256), 0, stream>>>(wz, uz, wr, ur, wh, uh, B1, B2);
  gru_gemm<1><<<dim3((M_ROWS / BM) * 8), dim3(256), 0, stream>>>(x, h, B1, nullptr, bz, br, out, rh, z16);
  gru_gemm<2><<<dim3((M_ROWS / BM) * 4), dim3(256), 0, stream>>>(x, h, B2, rh, bh, nullptr, out, nullptr, z16);
}

// Round 3
// 869.919 us; speedup vs baseline: 1.2218x; 1.0624x over previous
//
#include <hip/hip_runtime.h>
#include <cstdint>
#include <cstddef>

// GRU cell fused as two all-f16 MFMA GEMMs (m97 structure: global_load_lds staging).
// M = 131072 rows, A=128, H=512, K = 640.
// prep: x->x16, h->h16, weights -> transposed f16 panels B1 [1024][640], B2 [512][640]
// K1: [x16|h16] @ B1^T -> z (f16 ws / fp32 d_out), rh = sigmoid(ar)*h16 (f16 ws)
// K2: [x16|rh ] @ B2^T -> h_new = h16 + z*(tanh(ah)-h16)

#define M_ROWS 131072
#define A_DIM 128
#define H_DIM 512
#define K_TOT 640
#define BM 128
#define BN 128
#define BK 32
#define NSTEPS 20
#define XSTEPS 4

typedef _Float16 f16;
typedef _Float16 f16x8 __attribute__((ext_vector_type(8)));
typedef float f32x4 __attribute__((ext_vector_type(4)));

#define AS1 __attribute__((address_space(1)))
#define AS3 __attribute__((address_space(3)))

// async global->LDS, 16B/lane; LDS dest = wave-uniform base + lane*16 (linear).
__device__ __forceinline__ void gload_lds16(const void* g, void* l) {
  __builtin_amdgcn_global_load_lds((const AS1 unsigned int*)g,
                                   (AS3 unsigned int*)l, 16, 0, 0);
}

__device__ __forceinline__ float sigmoid_f(float v) { return 1.0f / (1.0f + __expf(-v)); }
__device__ __forceinline__ float tanh_f(float v) {
  float c = fminf(fmaxf(v, -15.0f), 15.0f);
  float e = __expf(2.0f * c);
  return (e - 1.0f) / (e + 1.0f);
}

// ---------------- prep kernels ----------------

__global__ void build_wcat(const float* __restrict__ wz, const float* __restrict__ uz,
                           const float* __restrict__ wr, const float* __restrict__ ur,
                           const float* __restrict__ wh, const float* __restrict__ uh,
                           f16* __restrict__ B1, f16* __restrict__ B2) {
  int idx = blockIdx.x * blockDim.x + threadIdx.x;
  const int n1 = 1024 * K_TOT;
  if (idx < n1) {
    int n = idx / K_TOT, k = idx % K_TOT;
    float v;
    if (k < A_DIM) v = (n < H_DIM) ? wz[k * H_DIM + n] : wr[k * H_DIM + (n - H_DIM)];
    else           v = (n < H_DIM) ? uz[(k - A_DIM) * H_DIM + n] : ur[(k - A_DIM) * H_DIM + (n - H_DIM)];
    B1[idx] = (f16)v;
  } else {
    int idx2 = idx - n1;
    if (idx2 < H_DIM * K_TOT) {
      int n = idx2 / K_TOT, k = idx2 % K_TOT;
      float v = (k < A_DIM) ? wh[k * H_DIM + n] : uh[(k - A_DIM) * H_DIM + n];
      B2[idx2] = (f16)v;
    }
  }
}

// convert two fp32 arrays to f16, 8 elems/thread, grid-stride
__global__ void cvt2_f32_f16(const float* __restrict__ a, long na,
                             const float* __restrict__ b, long nb,
                             f16* __restrict__ a16, f16* __restrict__ b16) {
  long i = (long)blockIdx.x * blockDim.x + threadIdx.x;
  const long stride = (long)gridDim.x * blockDim.x;
  const long tot = (na + nb) >> 3;
  for (; i < tot; i += stride) {
    const float* src; f16* dst; long e;
    if (i * 8 < na) { src = a; dst = a16; e = i * 8; }
    else            { src = b; dst = b16; e = i * 8 - na; }
    float4 v0 = *(const float4*)(src + e);
    float4 v1 = *(const float4*)(src + e + 4);
    f16x8 o;
    o[0] = (_Float16)v0.x; o[1] = (_Float16)v0.y; o[2] = (_Float16)v0.z; o[3] = (_Float16)v0.w;
    o[4] = (_Float16)v1.x; o[5] = (_Float16)v1.y; o[6] = (_Float16)v1.z; o[7] = (_Float16)v1.w;
    *(f16x8*)(dst + e) = o;
  }
}

// ---------------- fast GEMM (all-f16, gload_lds for A and B) ----------------
// LDS tile: [128 rows][32 k] f16, 64B/row = 4 x 16B slots. DMA writes linear;
// per-lane GLOBAL source chunk index is XORed with (row>>1)&3, and fragment
// reads use the same XOR -> 8-lane phases cover all 8 bank-quads (conflict-free).
template <int MODE>  // 1: N=1024 (z|r), A=[x16|h16].  2: N=512, A=[x16|rh].
__global__ __launch_bounds__(256, 4)
void gru_gemm16(const f16* __restrict__ A0, const f16* __restrict__ A1,
                const f16* __restrict__ h16, const f16* __restrict__ Bt,
                const float* __restrict__ bias0, const float* __restrict__ bias1,
                float* __restrict__ out, f16* __restrict__ rh_out,
                f16* __restrict__ z16) {
  constexpr int NBLK = (MODE == 1) ? 8 : 4;
  __shared__ __align__(16) char smem[2 * 16384];  // 2 bufs x (A 8KB + B 8KB)

  // XCD-bijective swizzle (grid multiple of 8): contiguous tile chunk per XCD,
  // nb fastest -> A panel + whole B panel L2-local.
  const int per = gridDim.x >> 3;
  const int b = blockIdx.x;
  const int tile = (b & 7) * per + (b >> 3);
  const int nb = tile & (NBLK - 1);
  const int mb = tile / NBLK;
  const int m0 = mb * BM;
  const int n0 = nb * BN;

  const int tid = threadIdx.x;
  const int lane = tid & 63;
  const int wid = tid >> 6;
  const int wm = wid >> 1;
  const int wn = wid & 1;
  const int r16 = lane & 15;
  const int kh = lane >> 4;

  f32x4 acc[4][4];
#pragma unroll
  for (int i = 0; i < 4; ++i)
#pragma unroll
    for (int j = 0; j < 4; ++j) acc[i][j] = (f32x4){0.f, 0.f, 0.f, 0.f};

  // per-lane staging geometry: s = chunk*64 + lane; row = s>>2; chunk-with-swizzle
  auto dma_A = [&](int t, int buf) {
    char* Aw = smem + buf * 16384;
    const f16* src = (t < XSTEPS) ? A0 : A1;
    const int ld = (t < XSTEPS) ? A_DIM : H_DIM;
    const int colb = (t < XSTEPS) ? t * BK : t * BK - A_DIM;
#pragma unroll
    for (int i = 0; i < 2; ++i) {
      const int chunk = wid * 2 + i;
      const int s = chunk * 64 + lane;
      const int row = s >> 2;
      const int c = (s & 3) ^ ((row >> 1) & 3);
      const f16* g = src + (size_t)(m0 + row) * ld + colb + c * 8;
      gload_lds16(g, Aw + chunk * 1024);
    }
  };
  auto dma_B = [&](int t, int buf) {
    char* Bw = smem + buf * 16384 + 8192;
#pragma unroll
    for (int i = 0; i < 2; ++i) {
      const int chunk = wid * 2 + i;
      const int s = chunk * 64 + lane;
      const int row = s >> 2;
      const int c = (s & 3) ^ ((row >> 1) & 3);
      const f16* g = Bt + (size_t)(n0 + row) * K_TOT + t * BK + c * 8;
      gload_lds16(g, Bw + chunk * 1024);
    }
  };

  dma_A(0, 0);
  dma_B(0, 0);
  __syncthreads();

  int cur = 0;
  for (int t = 0; t < NSTEPS; ++t) {
    if (t + 1 < NSTEPS) {
      dma_A(t + 1, cur ^ 1);
      dma_B(t + 1, cur ^ 1);
    }
    const char* Al = smem + cur * 16384;
    const char* Bl = Al + 8192;
    f16x8 aF[4], bF[4];
#pragma unroll
    for (int mi = 0; mi < 4; ++mi) {
      const int ra = wm * 64 + mi * 16 + r16;
      aF[mi] = *(const f16x8*)(Al + ra * 64 + ((kh ^ ((ra >> 1) & 3)) << 4));
    }
#pragma unroll
    for (int ni = 0; ni < 4; ++ni) {
      const int rb = wn * 64 + ni * 16 + r16;
      bF[ni] = *(const f16x8*)(Bl + rb * 64 + ((kh ^ ((rb >> 1) & 3)) << 4));
    }
#pragma unroll
    for (int mi = 0; mi < 4; ++mi)
#pragma unroll
      for (int ni = 0; ni < 4; ++ni)
        acc[mi][ni] = __builtin_amdgcn_mfma_f32_16x16x32_f16(aF[mi], bF[ni], acc[mi][ni], 0, 0, 0);
    __syncthreads();
    cur ^= 1;
  }

  // epilogue: C/D layout col=lane&15, row=(lane>>4)*4+reg
#pragma unroll
  for (int mi = 0; mi < 4; ++mi) {
#pragma unroll
    for (int ni = 0; ni < 4; ++ni) {
      const int n_g = n0 + wn * 64 + ni * 16 + r16;
#pragma unroll
      for (int r = 0; r < 4; ++r) {
        const int m_g = m0 + wm * 64 + mi * 16 + kh * 4 + r;
        float v = acc[mi][ni][r];
        if (MODE == 1) {
          if (n0 < H_DIM) {  // whole block is in the z half (block-uniform)
            float zv = sigmoid_f(v + bias0[n_g]);
            const size_t off = (size_t)m_g * H_DIM + n_g;
            if (z16) z16[off] = (f16)zv;
            else     out[off] = zv;
          } else {           // r half
            const int j = n_g - H_DIM;
            const size_t off = (size_t)m_g * H_DIM + j;
            float rv = sigmoid_f(v + bias1[j]);
            rh_out[off] = (f16)(rv * (float)h16[off]);
          }
        } else {
          const size_t off = (size_t)m_g * H_DIM + n_g;
          float th = tanh_f(v + bias0[n_g]);
          float zv = z16 ? (float)z16[off] : out[off];
          float hv = (float)h16[off];
          out[off] = fmaf(zv, th - hv, hv);
        }
      }
    }
  }
}

// ---------------- fallback GEMM (round-2 proven, fp32 A reg-staging) ----------------
template <int MODE>
__global__ __launch_bounds__(256, 2)
void gru_gemm_fb(const float* __restrict__ x, const float* __restrict__ h,
                 const f16* __restrict__ Bt, const f16* __restrict__ rh_in,
                 const float* __restrict__ bias0, const float* __restrict__ bias1,
                 float* __restrict__ out, f16* __restrict__ rh_out) {
  constexpr int NBLK = (MODE == 1) ? 8 : 4;
  __shared__ __align__(16) char smem[2 * 16384];

  const int per = gridDim.x >> 3;
  const int b = blockIdx.x;
  const int tile = (b & 7) * per + (b >> 3);
  const int nb = tile & (NBLK - 1);
  const int mb = tile / NBLK;
  const int m0 = mb * BM;
  const int n0 = nb * BN;

  const int tid = threadIdx.x;
  const int lane = tid & 63;
  const int wid = tid >> 6;
  const int wm = wid >> 1;
  const int wn = wid & 1;
  const int r16 = lane & 15;
  const int kh = lane >> 4;

  f32x4 acc[4][4];
#pragma unroll
  for (int i = 0; i < 4; ++i)
#pragma unroll
    for (int j = 0; j < 4; ++j) acc[i][j] = (f32x4){0.f, 0.f, 0.f, 0.f};

  float4 fa0, fa1, fa2, fa3;

  auto dma_B = [&](int t, int buf) {
    char* Bw = smem + buf * 16384 + 8192;
#pragma unroll
    for (int i = 0; i < 2; ++i) {
      const int chunk = wid * 2 + i;
      const int s = chunk * 64 + lane;
      const int row = s >> 2, c = s & 3;
      const f16* g = Bt + (size_t)(n0 + row) * K_TOT + t * BK + c * 8;
      gload_lds16(g, Bw + chunk * 1024);
    }
  };
  auto dma_A_rh = [&](int t, int buf) {
    char* Aw = smem + buf * 16384;
    const int col = t * BK - A_DIM;
#pragma unroll
    for (int i = 0; i < 2; ++i) {
      const int chunk = wid * 2 + i;
      const int s = chunk * 64 + lane;
      const int row = s >> 2, c = s & 3;
      const f16* g = rh_in + (size_t)(m0 + row) * H_DIM + col + c * 8;
      gload_lds16(g, Aw + chunk * 1024);
    }
  };
  auto load_A_regs = [&](int t) {
    const float* src = (t < XSTEPS) ? x : h;
    const int ld = (t < XSTEPS) ? A_DIM : H_DIM;
    const int col = (t < XSTEPS) ? t * BK : t * BK - A_DIM;
    {
      const int s = tid, row = s >> 2, c = s & 3;
      const float* g = src + (size_t)(m0 + row) * ld + col + c * 8;
      fa0 = *(const float4*)g;
      fa1 = *(const float4*)(g + 4);
    }
    {
      const int s = tid + 256, row = s >> 2, c = s & 3;
      const float* g = src + (size_t)(m0 + row) * ld + col + c * 8;
      fa2 = *(const float4*)g;
      fa3 = *(const float4*)(g + 4);
    }
  };
  auto write_A = [&](int buf) {
    char* Aw = smem + buf * 16384;
    f16x8 v;
    v[0] = (_Float16)fa0.x; v[1] = (_Float16)fa0.y; v[2] = (_Float16)fa0.z; v[3] = (_Float16)fa0.w;
    v[4] = (_Float16)fa1.x; v[5] = (_Float16)fa1.y; v[6] = (_Float16)fa1.z; v[7] = (_Float16)fa1.w;
    *(f16x8*)(Aw + tid * 16) = v;
    f16x8 w;
    w[0] = (_Float16)fa2.x; w[1] = (_Float16)fa2.y; w[2] = (_Float16)fa2.z; w[3] = (_Float16)fa2.w;
    w[4] = (_Float16)fa3.x; w[5] = (_Float16)fa3.y; w[6] = (_Float16)fa3.z; w[7] = (_Float16)fa3.w;
    *(f16x8*)(Aw + (tid + 256) * 16) = w;
  };

  dma_B(0, 0);
  load_A_regs(0);
  write_A(0);
  __syncthreads();

  int cur = 0;
  for (int t = 0; t < NSTEPS; ++t) {
    const int nxt = t + 1;
    const bool have = nxt < NSTEPS;
    const bool nxt_dma_A = (MODE == 2) && (nxt >= XSTEPS);
    if (have) {
      dma_B(nxt, cur ^ 1);
      if (nxt_dma_A) dma_A_rh(nxt, cur ^ 1);
      else load_A_regs(nxt);
    }
    const char* Al = smem + cur * 16384;
    const char* Bl = Al + 8192;
    f16x8 aF[4], bF[4];
#pragma unroll
    for (int mi = 0; mi < 4; ++mi)
      aF[mi] = *(const f16x8*)(Al + (wm * 64 + mi * 16 + r16) * 64 + kh * 16);
#pragma unroll
    for (int ni = 0; ni < 4; ++ni)
      bF[ni] = *(const f16x8*)(Bl + (wn * 64 + ni * 16 + r16) * 64 + kh * 16);
#pragma unroll
    for (int mi = 0; mi < 4; ++mi)
#pragma unroll
      for (int ni = 0; ni < 4; ++ni)
        acc[mi][ni] = __builtin_amdgcn_mfma_f32_16x16x32_f16(aF[mi], bF[ni], acc[mi][ni], 0, 0, 0);
    if (have && !nxt_dma_A) write_A(cur ^ 1);
    __syncthreads();
    cur ^= 1;
  }

#pragma unroll
  for (int mi = 0; mi < 4; ++mi) {
#pragma unroll
    for (int ni = 0; ni < 4; ++ni) {
      const int n_g = n0 + wn * 64 + ni * 16 + r16;
#pragma unroll
      for (int r = 0; r < 4; ++r) {
        const int m_g = m0 + wm * 64 + mi * 16 + kh * 4 + r;
        float v = acc[mi][ni][r];
        if (MODE == 1) {
          if (n_g < H_DIM) {
            out[(size_t)m_g * H_DIM + n_g] = sigmoid_f(v + bias0[n_g]);
          } else {
            const int j = n_g - H_DIM;
            const size_t off = (size_t)m_g * H_DIM + j;
            float rv = sigmoid_f(v + bias1[j]);
            rh_out[off] = (f16)(rv * h[off]);
          }
        } else {
          const size_t off = (size_t)m_g * H_DIM + n_g;
          float th = tanh_f(v + bias0[n_g]);
          float zv = out[off];
          float hv = h[off];
          out[off] = fmaf(zv, th - hv, hv);
        }
      }
    }
  }
}

extern "C" void kernel_launch(void* const* d_in, const int* in_sizes, int n_in,
                              void* d_out, int out_size, void* d_ws, size_t ws_size,
                              hipStream_t stream) {
  const float* x  = (const float*)d_in[0];
  const float* h  = (const float*)d_in[1];
  const float* wz = (const float*)d_in[2];
  const float* uz = (const float*)d_in[3];
  const float* bz = (const float*)d_in[4];
  const float* wr = (const float*)d_in[5];
  const float* ur = (const float*)d_in[6];
  const float* br = (const float*)d_in[7];
  const float* wh = (const float*)d_in[8];
  const float* uh = (const float*)d_in[9];
  const float* bh = (const float*)d_in[10];
  float* out = (float*)d_out;

  char* ws = (char*)d_ws;
  const size_t B1_B  = (size_t)1024 * K_TOT * 2;     //   1,310,720
  const size_t B2_B  = (size_t)H_DIM * K_TOT * 2;    //     655,360
  const size_t RH_B  = (size_t)M_ROWS * H_DIM * 2;   // 134,217,728
  const size_t X16_B = (size_t)M_ROWS * A_DIM * 2;   //  33,554,432
  const size_t H16_B = RH_B;
  const size_t Z16_B = RH_B;

  f16* B1 = (f16*)ws;
  f16* B2 = (f16*)(ws + B1_B);
  f16* rh = (f16*)(ws + B1_B + B2_B);

  const size_t need_base = B1_B + B2_B + RH_B + X16_B + H16_B;  // ~304 MB
  const int wtot = 1024 * K_TOT + H_DIM * K_TOT;

  if (ws_size >= need_base) {
    f16* x16 = (f16*)(ws + B1_B + B2_B + RH_B);
    f16* h16 = (f16*)(ws + B1_B + B2_B + RH_B + X16_B);
    f16* z16 = (ws_size >= need_base + Z16_B) ? (f16*)(ws + need_base) : nullptr;

    build_wcat<<<dim3((wtot + 255) / 256), dim3(256), 0, stream>>>(wz, uz, wr, ur, wh, uh, B1, B2);
    cvt2_f32_f16<<<dim3(4096), dim3(256), 0, stream>>>(
        x, (long)M_ROWS * A_DIM, h, (long)M_ROWS * H_DIM, x16, h16);
    gru_gemm16<1><<<dim3((M_ROWS / BM) * 8), dim3(256), 0, stream>>>(
        x16, h16, h16, B1, bz, br, out, rh, z16);
    gru_gemm16<2><<<dim3((M_ROWS / BM) * 4), dim3(256), 0, stream>>>(
        x16, rh, h16, B2, bh, nullptr, out, nullptr, z16);
  } else {
    // round-2 proven fallback (needs only ~136 MB of ws)
    build_wcat<<<dim3((wtot + 255) / 256), dim3(256), 0, stream>>>(wz, uz, wr, ur, wh, uh, B1, B2);
    gru_gemm_fb<1><<<dim3((M_ROWS / BM) * 8), dim3(256), 0, stream>>>(x, h, B1, nullptr, bz, br, out, rh);
    gru_gemm_fb<2><<<dim3((M_ROWS / BM) * 4), dim3(256), 0, stream>>>(x, h, B2, rh, bh, nullptr, out, rh);
  }
}